// Round 6
// baseline (2032.817 us; speedup 1.0000x reference)
//
#include <hip/hip_runtime.h>
#include <stdint.h>

#define T_STEPS 256
#define BATCH 64
#define DIM 1024
#define HID 1024
#define RANK 256
#define FOURH 4096
#define M1 (T_STEPS * BATCH) // 16384

typedef __bf16 bf16_t;
typedef bf16_t bf16x8 __attribute__((ext_vector_type(8)));
typedef float f32x4 __attribute__((ext_vector_type(4)));

union frag_cast { uint4 u; bf16x8 v; };
union b_cast { unsigned long long ll[2]; bf16x8 v; };

__device__ __forceinline__ bf16x8 load_frag(const unsigned short* p) {
  frag_cast c; c.u = *reinterpret_cast<const uint4*>(p); return c.v;
}
__device__ __forceinline__ unsigned short f2bf(float f) {
  union { float f; uint32_t u; } v; v.f = f;
  uint32_t u = v.u;
  return (unsigned short)((u + 0x7fffu + ((u >> 16) & 1u)) >> 16);
}
__device__ __forceinline__ float bf2f(unsigned short h) {
  union { uint32_t u; float f; } v; v.u = ((uint32_t)h) << 16; return v.f;
}

// Pack a [K x N] logical B matrix (f32 source) into MFMA B-fragment layout:
// frag (kc, nt): lane l slot s holds B[kc*32 + (l>>4)*8 + s][nt*16 + (l&15)].
__global__ void k_pack(const float* __restrict__ src, unsigned short* __restrict__ dst,
                       int NT, int ld, int transposed) {
  int id = blockIdx.x * blockDim.x + threadIdx.x;
  int lane = id & 63;
  int fi = id >> 6; // kc*NT + nt
  int nt = fi % NT, kc = fi / NT;
  int k0 = kc * 32 + ((lane >> 4) * 8);
  int n  = nt * 16 + (lane & 15);
  unsigned short vals[8];
  if (transposed) {
    const float* p = src + (size_t)n * ld + k0;
#pragma unroll
    for (int s = 0; s < 8; ++s) vals[s] = f2bf(p[s]);
  } else {
#pragma unroll
    for (int s = 0; s < 8; ++s) vals[s] = f2bf(src[(size_t)(k0 + s) * ld + n]);
  }
  union { unsigned short u16[8]; uint4 u; } o;
#pragma unroll
  for (int s = 0; s < 8; ++s) o.u16[s] = vals[s];
  *reinterpret_cast<uint4*>(dst + (size_t)id * 8) = o.u;
}

// corr_x[j] = dia_x[j%H] - dot(u_x[j%H,:], w_x[j,:]);  bias[j] = b_x[j]+b_h[j]
__global__ void k_coef(const float* __restrict__ u_x, const float* __restrict__ w_x,
                       const float* __restrict__ dia_x,
                       const float* __restrict__ b_x, const float* __restrict__ b_h,
                       float* __restrict__ corr, float* __restrict__ bias) {
  int wv = threadIdx.x >> 6, lane = threadIdx.x & 63;
  int j = blockIdx.x * 4 + wv;
  int e = j & (HID - 1);
  const float* up = u_x + (size_t)e * RANK + lane * 4;
  const float* wp = w_x + (size_t)j * RANK + lane * 4;
  float s = up[0] * wp[0] + up[1] * wp[1] + up[2] * wp[2] + up[3] * wp[3];
#pragma unroll
  for (int off = 32; off > 0; off >>= 1) s += __shfl_xor(s, off, 64);
  if (lane == 0) {
    corr[j] = dia_x[e] - s;
    bias[j] = b_x[j] + b_h[j];
  }
}

__global__ void k_init(const float* __restrict__ h0, unsigned short* __restrict__ hbuf,
                       unsigned int* __restrict__ slots) {
  int i = blockIdx.x * blockDim.x + threadIdx.x;
  if (i < 256 * 16) slots[i] = 0u;  // 256 padded barrier slots (64B each)
  hbuf[i] = f2bf(h0[i]); // exactly BATCH*HID threads
}

// C[M x 64*gridDim.x] = A_f32[M x 32*KC] @ packB, store bf16.
// dia != null: C is AhT [j][d]; override C[j][d] = dia[d] when d == j % HID.
__global__ void k_gemm_a32(const float* __restrict__ A, int lda,
                           const unsigned short* __restrict__ packB, int NTtot,
                           int KC, unsigned short* __restrict__ C, int ldc,
                           const float* __restrict__ dia) {
  int w = threadIdx.x >> 6, lane = threadIdx.x & 63;
  int q = lane >> 4, ln = lane & 15;
  int m0 = blockIdx.y * 64, n0 = blockIdx.x * 64;
  int arow = m0 + w * 16 + ln;
  f32x4 acc[4] = {};
  for (int kc = 0; kc < KC; ++kc) {
    const float* ap = A + (size_t)arow * lda + kc * 32 + q * 8;
    float4 x0 = *reinterpret_cast<const float4*>(ap);
    float4 x1 = *reinterpret_cast<const float4*>(ap + 4);
    bf16x8 a;
    a[0] = (bf16_t)x0.x; a[1] = (bf16_t)x0.y; a[2] = (bf16_t)x0.z; a[3] = (bf16_t)x0.w;
    a[4] = (bf16_t)x1.x; a[5] = (bf16_t)x1.y; a[6] = (bf16_t)x1.z; a[7] = (bf16_t)x1.w;
#pragma unroll
    for (int nt = 0; nt < 4; ++nt) {
      bf16x8 b = load_frag(packB + ((size_t)(kc * NTtot + blockIdx.x * 4 + nt) * 64 + lane) * 8);
      acc[nt] = __builtin_amdgcn_mfma_f32_16x16x32_bf16(a, b, acc[nt], 0, 0, 0);
    }
  }
#pragma unroll
  for (int nt = 0; nt < 4; ++nt) {
    int ccol = n0 + nt * 16 + ln;
#pragma unroll
    for (int r = 0; r < 4; ++r) {
      int crow = m0 + w * 16 + q * 4 + r;
      float v = acc[nt][r];
      if (dia != nullptr && ccol == (crow & (HID - 1))) v = dia[ccol];
      C[(size_t)crow * ldc + ccol] = f2bf(v);
    }
  }
}

// Repack AhT [j][d] (bf16) into per-(cg,gate,kc) B-fragment layout for k_rec.
__global__ void k_packAh(const unsigned short* __restrict__ AhT, unsigned short* __restrict__ dst) {
  int id = blockIdx.x * blockDim.x + threadIdx.x;
  int lane = id & 63;
  int fi = id >> 6;        // (cg*4+g)*32 + kc
  int kc = fi & 31;
  int g  = (fi >> 5) & 3;
  int cg = fi >> 7;
  int j  = g * HID + cg * 16 + (lane & 15);
  int d0 = kc * 32 + ((lane >> 4) * 8);
  uint4 v = *reinterpret_cast<const uint4*>(AhT + (size_t)j * HID + d0);
  *reinterpret_cast<uint4*>(dst + (size_t)id * 8) = v;
}

// gx[m][j] = P[m,:] @ w_xT[:,j] + x[m][j%H]*corr[j] + bias[j], store bf16.
__global__ void k_gemm2(const unsigned short* __restrict__ P,
                        const unsigned short* __restrict__ packWx,
                        const float* __restrict__ x,
                        const float* __restrict__ corr, const float* __restrict__ bias,
                        unsigned short* __restrict__ gx) {
  int w = threadIdx.x >> 6, lane = threadIdx.x & 63;
  int q = lane >> 4, ln = lane & 15;
  int m0 = blockIdx.y * 64, n0 = blockIdx.x * 64;
  int arow = m0 + w * 16 + ln;
  f32x4 acc[4] = {};
#pragma unroll
  for (int kc = 0; kc < 8; ++kc) {
    bf16x8 a = load_frag(P + (size_t)arow * RANK + kc * 32 + q * 8);
#pragma unroll
    for (int nt = 0; nt < 4; ++nt) {
      bf16x8 b = load_frag(packWx + ((size_t)(kc * 256 + blockIdx.x * 4 + nt) * 64 + lane) * 8);
      acc[nt] = __builtin_amdgcn_mfma_f32_16x16x32_bf16(a, b, acc[nt], 0, 0, 0);
    }
  }
#pragma unroll
  for (int nt = 0; nt < 4; ++nt) {
    int j = n0 + nt * 16 + ln;
    int e = j & (HID - 1);
    float cj = corr[j], bj = bias[j];
#pragma unroll
    for (int r = 0; r < 4; ++r) {
      int m = m0 + w * 16 + q * 4 + r;
      float v = acc[nt][r] + x[(size_t)m * DIM + e] * cj + bj;
      gx[(size_t)m * FOURH + j] = f2bf(v);
    }
  }
}

// Persistent recurrent kernel — R3-proven sync skeleton (global 256-slot
// barrier, all-256-thread spin) + two intra-block-safe upgrades:
//  - B fragments pinned in 128 VGPRs via volatile u64 loads (once, pre-loop).
//  - pre[][17] padding kills the 4-way LDS store conflict.
// h exchanged via agent-scope relaxed atomics (bypass L2, coherent at L3);
// no threadfence -> pAh/gx stay warm in per-XCD L2.
__global__ __launch_bounds__(256, 1) void k_rec(
    const unsigned short* __restrict__ pAh,
    const unsigned short* __restrict__ gx,
    const float* __restrict__ c0,
    unsigned short* __restrict__ hbuf,
    float* __restrict__ out,
    unsigned int* __restrict__ slots) {
  const int tid = threadIdx.x;
  const int w = tid >> 6, lane = tid & 63;
  const int q = lane >> 4, ln = lane & 15;
  const int blk = blockIdx.x;
  const int cg = blk & 63, bg = blk >> 6;

  // Pin B fragments in registers via volatile 8B scalar loads (cannot be
  // sunk/rematerialized; values stay live across the whole t-loop).
  unsigned long long bqa[32], bqb[32];
  const unsigned long long* pp = reinterpret_cast<const unsigned long long*>(pAh) +
                                 ((size_t)((cg * 4 + w) * 32) * 64 + lane) * 2;
#pragma unroll
  for (int kc = 0; kc < 32; ++kc) {
    bqa[kc] = *reinterpret_cast<const volatile unsigned long long*>(pp + (size_t)kc * 128);
    bqb[kc] = *reinterpret_cast<const volatile unsigned long long*>(pp + (size_t)kc * 128 + 1);
  }

  const int rb = tid >> 4, ee = tid & 15;
  const int brow = bg * 16 + rb;
  const int e = cg * 16 + ee;
  float c = c0[brow * HID + e];

  __shared__ unsigned short hstage[16][1032];  // +8 pad
  __shared__ float pre[4][16][17];             // +1 pad kills 4-way store conflict
  __shared__ unsigned short tile[16][16];

  unsigned int* myslot  = slots + (size_t)tid * 16;  // watch block `tid` (global)
  unsigned int* arrslot = slots + (size_t)blk * 16;  // my arrival slot

  size_t g0 = (size_t)brow * FOURH;
  float gx0 = bf2f(gx[g0 + e]);
  float gx1 = bf2f(gx[g0 + HID + e]);
  float gx2 = bf2f(gx[g0 + 2 * HID + e]);
  float gx3 = bf2f(gx[g0 + 3 * HID + e]);

  for (int t = 0; t < T_STEPS; ++t) {
    const int cur = t & 1;

    // Stage h(t): 32 KB as 8B agent atomic loads (L3 coherence point).
    const unsigned short* hb = hbuf + cur * (BATCH * HID);
#pragma unroll
    for (int it = 0; it < 16; ++it) {
      unsigned long long v = __hip_atomic_load(
          (const unsigned long long*)(hb + (size_t)(bg * 16 + it) * HID + tid * 4),
          __ATOMIC_RELAXED, __HIP_MEMORY_SCOPE_AGENT);
      *reinterpret_cast<unsigned long long*>(&hstage[it][tid * 4]) = v;
    }
    __syncthreads();

    // Prefetch gx(t+1) now; completes under the MFMA chain / spin.
    const int tn = (t + 1 < T_STEPS) ? (t + 1) : t;
    const size_t gn = ((size_t)tn * BATCH + brow) * FOURH;
    unsigned short n0 = gx[gn + e];
    unsigned short n1 = gx[gn + HID + e];
    unsigned short n2 = gx[gn + 2 * HID + e];
    unsigned short n3 = gx[gn + 3 * HID + e];

    f32x4 a0 = {}, a1 = {}, a2 = {}, a3 = {};
#pragma unroll
    for (int kc = 0; kc < 32; kc += 4) {
      b_cast b0, b1, b2, b3;
      b0.ll[0] = bqa[kc];     b0.ll[1] = bqb[kc];
      b1.ll[0] = bqa[kc + 1]; b1.ll[1] = bqb[kc + 1];
      b2.ll[0] = bqa[kc + 2]; b2.ll[1] = bqb[kc + 2];
      b3.ll[0] = bqa[kc + 3]; b3.ll[1] = bqb[kc + 3];
      a0 = __builtin_amdgcn_mfma_f32_16x16x32_bf16(load_frag(&hstage[ln][(kc    ) * 32 + q * 8]), b0.v, a0, 0, 0, 0);
      a1 = __builtin_amdgcn_mfma_f32_16x16x32_bf16(load_frag(&hstage[ln][(kc + 1) * 32 + q * 8]), b1.v, a1, 0, 0, 0);
      a2 = __builtin_amdgcn_mfma_f32_16x16x32_bf16(load_frag(&hstage[ln][(kc + 2) * 32 + q * 8]), b2.v, a2, 0, 0, 0);
      a3 = __builtin_amdgcn_mfma_f32_16x16x32_bf16(load_frag(&hstage[ln][(kc + 3) * 32 + q * 8]), b3.v, a3, 0, 0, 0);
    }
#pragma unroll
    for (int r = 0; r < 4; ++r)
      pre[w][q * 4 + r][ln] = (a0[r] + a1[r]) + (a2[r] + a3[r]);
    __syncthreads();

    float p0 = pre[0][rb][ee] + gx0;
    float p1 = pre[1][rb][ee] + gx1;
    float p2 = pre[2][rb][ee] + gx2;
    float p3 = pre[3][rb][ee] + gx3;

    float gi = 1.f / (1.f + __expf(-p0));
    float gf = 1.f / (1.f + __expf(-p1));
    float go = 1.f / (1.f + __expf(-p2));
    float gn_ = tanhf(p3);
    c = gf * c + gi * gn_;
    float hn = go * tanhf(c);
    out[((size_t)t * BATCH + brow) * HID + e] = hn;
    tile[rb][ee] = f2bf(hn);
    if (t == T_STEPS - 1) {
      out[(size_t)T_STEPS * BATCH * HID + brow * HID + e] = hn;              // h_f
      out[(size_t)T_STEPS * BATCH * HID + BATCH * HID + brow * HID + e] = c; // c_f
    }
    __syncthreads();  // tile complete

    // Publish h(t+1): wave 0 only (64 u64 agent atomic stores to L3).
    if (tid < 64) {
      int r2 = tid >> 2, gsel = tid & 3;
      unsigned long long v =
          *reinterpret_cast<const unsigned long long*>(&tile[r2][gsel * 4]);
      __hip_atomic_store(
          (unsigned long long*)(hbuf + (size_t)(cur ^ 1) * (BATCH * HID) +
                                (size_t)(bg * 16 + r2) * HID + cg * 16 + gsel * 4),
          v, __ATOMIC_RELAXED, __HIP_MEMORY_SCOPE_AGENT);
    }
    __syncthreads();  // wave0 vmcnt(0) drained -> h stores are at L3
    if (tid == 0)
      __hip_atomic_store(arrslot, (unsigned int)(t + 1), __ATOMIC_RELAXED,
                         __HIP_MEMORY_SCOPE_AGENT);
    while (__hip_atomic_load(myslot, __ATOMIC_RELAXED, __HIP_MEMORY_SCOPE_AGENT) <
           (unsigned int)(t + 1))
      __builtin_amdgcn_s_sleep(1);
    __syncthreads();  // all 256 slots observed >= t+1 by this block

    gx0 = bf2f(n0); gx1 = bf2f(n1); gx2 = bf2f(n2); gx3 = bf2f(n3);
  }
}

extern "C" void kernel_launch(void* const* d_in, const int* in_sizes, int n_in,
                              void* d_out, int out_size, void* d_ws, size_t ws_size,
                              hipStream_t stream) {
  const float* x     = (const float*)d_in[0];
  const float* h0    = (const float*)d_in[1];
  const float* c0    = (const float*)d_in[2];
  const float* u_x   = (const float*)d_in[3];
  const float* u_h   = (const float*)d_in[4];
  const float* w_x   = (const float*)d_in[5];
  const float* w_h   = (const float*)d_in[6];
  const float* b_x   = (const float*)d_in[7];
  const float* b_h   = (const float*)d_in[8];
  const float* dia_x = (const float*)d_in[9];
  const float* dia_h = (const float*)d_in[10];
  float* out = (float*)d_out;
  (void)in_sizes; (void)n_in; (void)out_size; (void)ws_size;

  char* base = (char*)d_ws;
  size_t off = 0;
  auto alloc = [&](size_t bytes) -> void* {
    void* p = base + off;
    off = (off + bytes + 255) & ~(size_t)255;
    return p;
  };
  unsigned short* pUx  = (unsigned short*)alloc((size_t)32 * 16 * 64 * 8 * 2);
  unsigned short* pUhT = (unsigned short*)alloc((size_t)8 * 64 * 64 * 8 * 2);
  unsigned short* pWx  = (unsigned short*)alloc((size_t)8 * 256 * 64 * 8 * 2);
  float* corr = (float*)alloc((size_t)FOURH * 4);
  float* bias = (float*)alloc((size_t)FOURH * 4);
  unsigned short* hbuf = (unsigned short*)alloc((size_t)2 * BATCH * HID * 2);
  unsigned int* slots  = (unsigned int*)alloc((size_t)256 * 16 * 4);  // 64B/slot
  unsigned short* P    = (unsigned short*)alloc((size_t)M1 * RANK * 2);
  unsigned short* AhT  = (unsigned short*)alloc((size_t)FOURH * HID * 2);
  unsigned short* pAh  = (unsigned short*)alloc((size_t)64 * 4 * 32 * 64 * 8 * 2);
  unsigned short* gx   = (unsigned short*)alloc((size_t)M1 * FOURH * 2);

  // B-operand packs (one-time, reused by GEMMs / recurrence)
  k_pack<<<128, 256, 0, stream>>>(u_x, pUx, 16, RANK, 0);   // G1 B: u_x [1024 x 256]
  k_pack<<<128, 256, 0, stream>>>(u_h, pUhT, 64, RANK, 1);  // G3 B: u_hT [256 x 1024]
  k_pack<<<512, 256, 0, stream>>>(w_x, pWx, 256, RANK, 1);  // G2 B: w_xT [256 x 4096]
  k_coef<<<1024, 256, 0, stream>>>(u_x, w_x, dia_x, b_x, b_h, corr, bias);
  k_init<<<256, 256, 0, stream>>>(h0, hbuf, slots);
  // G1: P[16384 x 256] = X @ u_x
  k_gemm_a32<<<dim3(4, 256), 256, 0, stream>>>(x, DIM, pUx, 16, 32, P, RANK, nullptr);
  // G3: AhT[4096 x 1024] = w_h @ u_hT, diagonal overridden with dia_h
  k_gemm_a32<<<dim3(16, 64), 256, 0, stream>>>(w_h, RANK, pUhT, 64, 8, AhT, HID, dia_h);
  k_packAh<<<2048, 256, 0, stream>>>(AhT, pAh);
  // G2: gx = P @ w_xT + x*corr + bias  (bf16)
  k_gemm2<<<dim3(64, 256), 256, 0, stream>>>(P, pWx, x, corr, bias, gx);
  // Persistent recurrence
  k_rec<<<256, 256, 0, stream>>>(pAh, gx, c0, hbuf, out, slots);
}

// Round 7
// 1931.180 us; speedup vs baseline: 1.0526x; 1.0526x over previous
//
#include <hip/hip_runtime.h>
#include <stdint.h>

#define T_STEPS 256
#define BATCH 64
#define DIM 1024
#define HID 1024
#define RANK 256
#define FOURH 4096
#define M1 (T_STEPS * BATCH) // 16384

typedef __bf16 bf16_t;
typedef bf16_t bf16x8 __attribute__((ext_vector_type(8)));
typedef float f32x4 __attribute__((ext_vector_type(4)));

union frag_cast { uint4 u; bf16x8 v; };
union b_cast { unsigned long long ll[2]; bf16x8 v; };

__device__ __forceinline__ bf16x8 load_frag(const unsigned short* p) {
  frag_cast c; c.u = *reinterpret_cast<const uint4*>(p); return c.v;
}
__device__ __forceinline__ unsigned short f2bf(float f) {
  union { float f; uint32_t u; } v; v.f = f;
  uint32_t u = v.u;
  return (unsigned short)((u + 0x7fffu + ((u >> 16) & 1u)) >> 16);
}
__device__ __forceinline__ float bf2f(unsigned short h) {
  union { uint32_t u; float f; } v; v.u = ((uint32_t)h) << 16; return v.f;
}

// Pack a [K x N] logical B matrix (f32 source) into MFMA B-fragment layout:
// frag (kc, nt): lane l slot s holds B[kc*32 + (l>>4)*8 + s][nt*16 + (l&15)].
__global__ void k_pack(const float* __restrict__ src, unsigned short* __restrict__ dst,
                       int NT, int ld, int transposed) {
  int id = blockIdx.x * blockDim.x + threadIdx.x;
  int lane = id & 63;
  int fi = id >> 6; // kc*NT + nt
  int nt = fi % NT, kc = fi / NT;
  int k0 = kc * 32 + ((lane >> 4) * 8);
  int n  = nt * 16 + (lane & 15);
  unsigned short vals[8];
  if (transposed) {
    const float* p = src + (size_t)n * ld + k0;
#pragma unroll
    for (int s = 0; s < 8; ++s) vals[s] = f2bf(p[s]);
  } else {
#pragma unroll
    for (int s = 0; s < 8; ++s) vals[s] = f2bf(src[(size_t)(k0 + s) * ld + n]);
  }
  union { unsigned short u16[8]; uint4 u; } o;
#pragma unroll
  for (int s = 0; s < 8; ++s) o.u16[s] = vals[s];
  *reinterpret_cast<uint4*>(dst + (size_t)id * 8) = o.u;
}

// corr_x[j] = dia_x[j%H] - dot(u_x[j%H,:], w_x[j,:]);  bias[j] = b_x[j]+b_h[j]
__global__ void k_coef(const float* __restrict__ u_x, const float* __restrict__ w_x,
                       const float* __restrict__ dia_x,
                       const float* __restrict__ b_x, const float* __restrict__ b_h,
                       float* __restrict__ corr, float* __restrict__ bias) {
  int wv = threadIdx.x >> 6, lane = threadIdx.x & 63;
  int j = blockIdx.x * 4 + wv;
  int e = j & (HID - 1);
  const float* up = u_x + (size_t)e * RANK + lane * 4;
  const float* wp = w_x + (size_t)j * RANK + lane * 4;
  float s = up[0] * wp[0] + up[1] * wp[1] + up[2] * wp[2] + up[3] * wp[3];
#pragma unroll
  for (int off = 32; off > 0; off >>= 1) s += __shfl_xor(s, off, 64);
  if (lane == 0) {
    corr[j] = dia_x[e] - s;
    bias[j] = b_x[j] + b_h[j];
  }
}

__global__ void k_init(const float* __restrict__ h0, unsigned short* __restrict__ hbuf,
                       unsigned int* __restrict__ slots) {
  int i = blockIdx.x * blockDim.x + threadIdx.x;
  if (i < 256 * 16) slots[i] = 0u;  // 256 padded barrier slots (64B each)
  hbuf[i] = f2bf(h0[i]); // exactly BATCH*HID threads
}

// C[M x 64*gridDim.x] = A_f32[M x 32*KC] @ packB, store bf16.
// dia != null: C is AhT [j][d]; override C[j][d] = dia[d] when d == j % HID.
__global__ void k_gemm_a32(const float* __restrict__ A, int lda,
                           const unsigned short* __restrict__ packB, int NTtot,
                           int KC, unsigned short* __restrict__ C, int ldc,
                           const float* __restrict__ dia) {
  int w = threadIdx.x >> 6, lane = threadIdx.x & 63;
  int q = lane >> 4, ln = lane & 15;
  int m0 = blockIdx.y * 64, n0 = blockIdx.x * 64;
  int arow = m0 + w * 16 + ln;
  f32x4 acc[4] = {};
  for (int kc = 0; kc < KC; ++kc) {
    const float* ap = A + (size_t)arow * lda + kc * 32 + q * 8;
    float4 x0 = *reinterpret_cast<const float4*>(ap);
    float4 x1 = *reinterpret_cast<const float4*>(ap + 4);
    bf16x8 a;
    a[0] = (bf16_t)x0.x; a[1] = (bf16_t)x0.y; a[2] = (bf16_t)x0.z; a[3] = (bf16_t)x0.w;
    a[4] = (bf16_t)x1.x; a[5] = (bf16_t)x1.y; a[6] = (bf16_t)x1.z; a[7] = (bf16_t)x1.w;
#pragma unroll
    for (int nt = 0; nt < 4; ++nt) {
      bf16x8 b = load_frag(packB + ((size_t)(kc * NTtot + blockIdx.x * 4 + nt) * 64 + lane) * 8);
      acc[nt] = __builtin_amdgcn_mfma_f32_16x16x32_bf16(a, b, acc[nt], 0, 0, 0);
    }
  }
#pragma unroll
  for (int nt = 0; nt < 4; ++nt) {
    int ccol = n0 + nt * 16 + ln;
#pragma unroll
    for (int r = 0; r < 4; ++r) {
      int crow = m0 + w * 16 + q * 4 + r;
      float v = acc[nt][r];
      if (dia != nullptr && ccol == (crow & (HID - 1))) v = dia[ccol];
      C[(size_t)crow * ldc + ccol] = f2bf(v);
    }
  }
}

// Repack AhT [j][d] (bf16) into per-(cg,gate,kc) B-fragment layout for k_rec.
__global__ void k_packAh(const unsigned short* __restrict__ AhT, unsigned short* __restrict__ dst) {
  int id = blockIdx.x * blockDim.x + threadIdx.x;
  int lane = id & 63;
  int fi = id >> 6;        // (cg*4+g)*32 + kc
  int kc = fi & 31;
  int g  = (fi >> 5) & 3;
  int cg = fi >> 7;
  int j  = g * HID + cg * 16 + (lane & 15);
  int d0 = kc * 32 + ((lane >> 4) * 8);
  uint4 v = *reinterpret_cast<const uint4*>(AhT + (size_t)j * HID + d0);
  *reinterpret_cast<uint4*>(dst + (size_t)id * 8) = v;
}

// gx[m][j] = P[m,:] @ w_xT[:,j] + x[m][j%H]*corr[j] + bias[j], store bf16.
__global__ void k_gemm2(const unsigned short* __restrict__ P,
                        const unsigned short* __restrict__ packWx,
                        const float* __restrict__ x,
                        const float* __restrict__ corr, const float* __restrict__ bias,
                        unsigned short* __restrict__ gx) {
  int w = threadIdx.x >> 6, lane = threadIdx.x & 63;
  int q = lane >> 4, ln = lane & 15;
  int m0 = blockIdx.y * 64, n0 = blockIdx.x * 64;
  int arow = m0 + w * 16 + ln;
  f32x4 acc[4] = {};
#pragma unroll
  for (int kc = 0; kc < 8; ++kc) {
    bf16x8 a = load_frag(P + (size_t)arow * RANK + kc * 32 + q * 8);
#pragma unroll
    for (int nt = 0; nt < 4; ++nt) {
      bf16x8 b = load_frag(packWx + ((size_t)(kc * 256 + blockIdx.x * 4 + nt) * 64 + lane) * 8);
      acc[nt] = __builtin_amdgcn_mfma_f32_16x16x32_bf16(a, b, acc[nt], 0, 0, 0);
    }
  }
#pragma unroll
  for (int nt = 0; nt < 4; ++nt) {
    int j = n0 + nt * 16 + ln;
    int e = j & (HID - 1);
    float cj = corr[j], bj = bias[j];
#pragma unroll
    for (int r = 0; r < 4; ++r) {
      int m = m0 + w * 16 + q * 4 + r;
      float v = acc[nt][r] + x[(size_t)m * DIM + e] * cj + bj;
      gx[(size_t)m * FOURH + j] = f2bf(v);
    }
  }
}

// Persistent recurrent kernel — R3/R6-proven sync skeleton (global 256-slot
// barrier, all-256-thread spin).
//  - amdgpu_waves_per_eu(1,1): true occupancy IS 1 wave/EU (4 waves, 1
//    block/CU); raises VGPR budget to ~512 so the volatile-loaded B
//    fragments live in registers, not scratch (R6: VGPR=96 => scratch).
//  - out HBM store moved after the slot publish: out is never read on
//    device, so ordering vs the barrier is irrelevant; its store-ack now
//    overlaps the spin instead of sitting in the pre-publish drain.
// h exchanged via agent-scope relaxed atomics (bypass L2, coherent at L3);
// no threadfence -> pAh/gx stay warm in per-XCD L2.
__global__ __launch_bounds__(256, 1) __attribute__((amdgpu_waves_per_eu(1, 1)))
void k_rec(
    const unsigned short* __restrict__ pAh,
    const unsigned short* __restrict__ gx,
    const float* __restrict__ c0,
    unsigned short* __restrict__ hbuf,
    float* __restrict__ out,
    unsigned int* __restrict__ slots) {
  const int tid = threadIdx.x;
  const int w = tid >> 6, lane = tid & 63;
  const int q = lane >> 4, ln = lane & 15;
  const int blk = blockIdx.x;
  const int cg = blk & 63, bg = blk >> 6;

  // Pin B fragments in registers via volatile 8B scalar loads (cannot be
  // sunk/rematerialized; with waves_per_eu(1,1) they stay in VGPRs).
  unsigned long long bqa[32], bqb[32];
  const unsigned long long* pp = reinterpret_cast<const unsigned long long*>(pAh) +
                                 ((size_t)((cg * 4 + w) * 32) * 64 + lane) * 2;
#pragma unroll
  for (int kc = 0; kc < 32; ++kc) {
    bqa[kc] = *reinterpret_cast<const volatile unsigned long long*>(pp + (size_t)kc * 128);
    bqb[kc] = *reinterpret_cast<const volatile unsigned long long*>(pp + (size_t)kc * 128 + 1);
  }

  const int rb = tid >> 4, ee = tid & 15;
  const int brow = bg * 16 + rb;
  const int e = cg * 16 + ee;
  float c = c0[brow * HID + e];

  __shared__ unsigned short hstage[16][1032];  // +8 pad
  __shared__ float pre[4][16][17];             // +1 pad
  __shared__ unsigned short tile[16][16];

  unsigned int* myslot  = slots + (size_t)tid * 16;  // watch block `tid` (global)
  unsigned int* arrslot = slots + (size_t)blk * 16;  // my arrival slot

  size_t g0 = (size_t)brow * FOURH;
  float gx0 = bf2f(gx[g0 + e]);
  float gx1 = bf2f(gx[g0 + HID + e]);
  float gx2 = bf2f(gx[g0 + 2 * HID + e]);
  float gx3 = bf2f(gx[g0 + 3 * HID + e]);

  for (int t = 0; t < T_STEPS; ++t) {
    const int cur = t & 1;

    // Stage h(t): 32 KB as 8B agent atomic loads (L3 coherence point).
    const unsigned short* hb = hbuf + cur * (BATCH * HID);
#pragma unroll
    for (int it = 0; it < 16; ++it) {
      unsigned long long v = __hip_atomic_load(
          (const unsigned long long*)(hb + (size_t)(bg * 16 + it) * HID + tid * 4),
          __ATOMIC_RELAXED, __HIP_MEMORY_SCOPE_AGENT);
      *reinterpret_cast<unsigned long long*>(&hstage[it][tid * 4]) = v;
    }
    __syncthreads();

    // Prefetch gx(t+1) now; completes under the MFMA chain / spin.
    const int tn = (t + 1 < T_STEPS) ? (t + 1) : t;
    const size_t gn = ((size_t)tn * BATCH + brow) * FOURH;
    unsigned short n0 = gx[gn + e];
    unsigned short n1 = gx[gn + HID + e];
    unsigned short n2 = gx[gn + 2 * HID + e];
    unsigned short n3 = gx[gn + 3 * HID + e];

    f32x4 a0 = {}, a1 = {}, a2 = {}, a3 = {};
#pragma unroll
    for (int kc = 0; kc < 32; kc += 4) {
      b_cast b0, b1, b2, b3;
      b0.ll[0] = bqa[kc];     b0.ll[1] = bqb[kc];
      b1.ll[0] = bqa[kc + 1]; b1.ll[1] = bqb[kc + 1];
      b2.ll[0] = bqa[kc + 2]; b2.ll[1] = bqb[kc + 2];
      b3.ll[0] = bqa[kc + 3]; b3.ll[1] = bqb[kc + 3];
      a0 = __builtin_amdgcn_mfma_f32_16x16x32_bf16(load_frag(&hstage[ln][(kc    ) * 32 + q * 8]), b0.v, a0, 0, 0, 0);
      a1 = __builtin_amdgcn_mfma_f32_16x16x32_bf16(load_frag(&hstage[ln][(kc + 1) * 32 + q * 8]), b1.v, a1, 0, 0, 0);
      a2 = __builtin_amdgcn_mfma_f32_16x16x32_bf16(load_frag(&hstage[ln][(kc + 2) * 32 + q * 8]), b2.v, a2, 0, 0, 0);
      a3 = __builtin_amdgcn_mfma_f32_16x16x32_bf16(load_frag(&hstage[ln][(kc + 3) * 32 + q * 8]), b3.v, a3, 0, 0, 0);
    }
#pragma unroll
    for (int r = 0; r < 4; ++r)
      pre[w][q * 4 + r][ln] = (a0[r] + a1[r]) + (a2[r] + a3[r]);
    __syncthreads();

    float p0 = pre[0][rb][ee] + gx0;
    float p1 = pre[1][rb][ee] + gx1;
    float p2 = pre[2][rb][ee] + gx2;
    float p3 = pre[3][rb][ee] + gx3;

    float gi = 1.f / (1.f + __expf(-p0));
    float gf = 1.f / (1.f + __expf(-p1));
    float go = 1.f / (1.f + __expf(-p2));
    float gn_ = tanhf(p3);
    c = gf * c + gi * gn_;
    float hn = go * tanhf(c);
    tile[rb][ee] = f2bf(hn);
    __syncthreads();  // tile complete

    // Publish h(t+1): wave 0 only (64 u64 agent atomic stores to L3).
    if (tid < 64) {
      int r2 = tid >> 2, gsel = tid & 3;
      unsigned long long v =
          *reinterpret_cast<const unsigned long long*>(&tile[r2][gsel * 4]);
      __hip_atomic_store(
          (unsigned long long*)(hbuf + (size_t)(cur ^ 1) * (BATCH * HID) +
                                (size_t)(bg * 16 + r2) * HID + cg * 16 + gsel * 4),
          v, __ATOMIC_RELAXED, __HIP_MEMORY_SCOPE_AGENT);
    }
    __syncthreads();  // wave0 vmcnt(0) drained -> h stores are at L3
    if (tid == 0)
      __hip_atomic_store(arrslot, (unsigned int)(t + 1), __ATOMIC_RELAXED,
                         __HIP_MEMORY_SCOPE_AGENT);

    // out stores AFTER the publish: never read on device, ack overlaps spin.
    out[((size_t)t * BATCH + brow) * HID + e] = hn;
    if (t == T_STEPS - 1) {
      out[(size_t)T_STEPS * BATCH * HID + brow * HID + e] = hn;              // h_f
      out[(size_t)T_STEPS * BATCH * HID + BATCH * HID + brow * HID + e] = c; // c_f
    }

    while (__hip_atomic_load(myslot, __ATOMIC_RELAXED, __HIP_MEMORY_SCOPE_AGENT) <
           (unsigned int)(t + 1))
      __builtin_amdgcn_s_sleep(1);
    __syncthreads();  // all 256 slots observed >= t+1 by this block

    gx0 = bf2f(n0); gx1 = bf2f(n1); gx2 = bf2f(n2); gx3 = bf2f(n3);
  }
}

extern "C" void kernel_launch(void* const* d_in, const int* in_sizes, int n_in,
                              void* d_out, int out_size, void* d_ws, size_t ws_size,
                              hipStream_t stream) {
  const float* x     = (const float*)d_in[0];
  const float* h0    = (const float*)d_in[1];
  const float* c0    = (const float*)d_in[2];
  const float* u_x   = (const float*)d_in[3];
  const float* u_h   = (const float*)d_in[4];
  const float* w_x   = (const float*)d_in[5];
  const float* w_h   = (const float*)d_in[6];
  const float* b_x   = (const float*)d_in[7];
  const float* b_h   = (const float*)d_in[8];
  const float* dia_x = (const float*)d_in[9];
  const float* dia_h = (const float*)d_in[10];
  float* out = (float*)d_out;
  (void)in_sizes; (void)n_in; (void)out_size; (void)ws_size;

  char* base = (char*)d_ws;
  size_t off = 0;
  auto alloc = [&](size_t bytes) -> void* {
    void* p = base + off;
    off = (off + bytes + 255) & ~(size_t)255;
    return p;
  };
  unsigned short* pUx  = (unsigned short*)alloc((size_t)32 * 16 * 64 * 8 * 2);
  unsigned short* pUhT = (unsigned short*)alloc((size_t)8 * 64 * 64 * 8 * 2);
  unsigned short* pWx  = (unsigned short*)alloc((size_t)8 * 256 * 64 * 8 * 2);
  float* corr = (float*)alloc((size_t)FOURH * 4);
  float* bias = (float*)alloc((size_t)FOURH * 4);
  unsigned short* hbuf = (unsigned short*)alloc((size_t)2 * BATCH * HID * 2);
  unsigned int* slots  = (unsigned int*)alloc((size_t)256 * 16 * 4);  // 64B/slot
  unsigned short* P    = (unsigned short*)alloc((size_t)M1 * RANK * 2);
  unsigned short* AhT  = (unsigned short*)alloc((size_t)FOURH * HID * 2);
  unsigned short* pAh  = (unsigned short*)alloc((size_t)64 * 4 * 32 * 64 * 8 * 2);
  unsigned short* gx   = (unsigned short*)alloc((size_t)M1 * FOURH * 2);

  // B-operand packs (one-time, reused by GEMMs / recurrence)
  k_pack<<<128, 256, 0, stream>>>(u_x, pUx, 16, RANK, 0);   // G1 B: u_x [1024 x 256]
  k_pack<<<128, 256, 0, stream>>>(u_h, pUhT, 64, RANK, 1);  // G3 B: u_hT [256 x 1024]
  k_pack<<<512, 256, 0, stream>>>(w_x, pWx, 256, RANK, 1);  // G2 B: w_xT [256 x 4096]
  k_coef<<<1024, 256, 0, stream>>>(u_x, w_x, dia_x, b_x, b_h, corr, bias);
  k_init<<<256, 256, 0, stream>>>(h0, hbuf, slots);
  // G1: P[16384 x 256] = X @ u_x
  k_gemm_a32<<<dim3(4, 256), 256, 0, stream>>>(x, DIM, pUx, 16, 32, P, RANK, nullptr);
  // G3: AhT[4096 x 1024] = w_h @ u_hT, diagonal overridden with dia_h
  k_gemm_a32<<<dim3(16, 64), 256, 0, stream>>>(w_h, RANK, pUhT, 64, 8, AhT, HID, dia_h);
  k_packAh<<<2048, 256, 0, stream>>>(AhT, pAh);
  // G2: gx = P @ w_xT + x*corr + bias  (bf16)
  k_gemm2<<<dim3(64, 256), 256, 0, stream>>>(P, pWx, x, corr, bias, gx);
  // Persistent recurrence
  k_rec<<<256, 256, 0, stream>>>(pAh, gx, c0, hbuf, out, slots);
}